// Round 3
// baseline (290.922 us; speedup 1.0000x reference)
//
#include <hip/hip_runtime.h>

#define NTH 256
#define NBOX 16384
#define NCLSIN 91
#define NCLS 90
#define MAXSEL 100
#define TOPK 200
#define TSEL 256      // fallback radix-select size
#define CAP 1024      // candidate list capacity per (b,c)
#define CBCAP 512     // prefetched candidate boxes
#define BINS 2048
#define GRP 8         // BINS / NTH
#define T0 0.985f     // band threshold: E[hits]=246, sigma~16; refill guards exactness

// order-preserving fp32 <-> u32 (strictly monotone for all non-NaN)
__device__ __forceinline__ unsigned fmap(float f) {
    unsigned u = __float_as_uint(f);
    return (u & 0x80000000u) ? ~u : (u | 0x80000000u);
}
__device__ __forceinline__ float funmap(unsigned u) {
    unsigned b = (u & 0x80000000u) ? (u ^ 0x80000000u) : ~u;
    return __uint_as_float(b);
}

// exact reference IoU>0.5 test (same op order, real IEEE div, no FMA)
__device__ __forceinline__ bool sup_test(float4 s, float sa, float4 c, float ca) {
    float y1 = fmaxf(s.x, c.x);
    float x1 = fmaxf(s.y, c.y);
    float y2 = fminf(s.z, c.z);
    float x2 = fminf(s.w, c.w);
    float dy = fmaxf(__fsub_rn(y2, y1), 0.f);
    float dx = fmaxf(__fsub_rn(x2, x1), 0.f);
    float inter = __fmul_rn(dy, dx);
    float uni = __fsub_rn(__fadd_rn(sa, ca), inter);
    return (uni > 0.f) && (__fdiv_rn(inter, uni) > 0.5f);
}

__device__ __forceinline__ void bin_select(unsigned* hist, unsigned* gbuf,
                                           int* sh_g, int* sh_b, unsigned* sh_pb,
                                           int tid, unsigned need) {
    unsigned gs = 0;
#pragma unroll
    for (int q = 0; q < GRP; ++q) gs += hist[tid * GRP + q];
    gbuf[tid] = gs;
    __syncthreads();
    for (int off = 1; off < NTH; off <<= 1) {
        unsigned add = (tid >= off) ? gbuf[tid - off] : 0u;
        __syncthreads();
        gbuf[tid] += add;
        __syncthreads();
    }
    if (tid == 0) *sh_g = NTH - 1;
    __syncthreads();
    if (gbuf[tid] >= need && (tid == 0 || gbuf[tid - 1] < need)) *sh_g = tid;
    __syncthreads();
    if (tid == 0) {
        int g = *sh_g;
        unsigned acc = (g > 0) ? gbuf[g - 1] : 0u;
        int bs = g * GRP + (GRP - 1);
        unsigned pb = acc;
#pragma unroll
        for (int q = 0; q < GRP; ++q) {
            acc += hist[g * GRP + q];
            if (acc >= need) { bs = g * GRP + q; pb = acc; break; }
            pb = acc;
        }
        *sh_b = bs; *sh_pb = pb;
    }
    __syncthreads();
}

// ---------------------------------------------------------------------------
// Kernel 0: stream scores once; append (key, idx) for s > T0 into per-(b,c)
// candidate lists via ballot-aggregated atomics. ~2% hit rate.
// ---------------------------------------------------------------------------
__global__ __launch_bounds__(NTH) void filter_k(const float* __restrict__ in,
                                                unsigned long long* __restrict__ cand_g,
                                                int* __restrict__ cnt_g) {
    __shared__ float tile[64 * 93];  // 64 boxes x 91 cls, pad 93 (conflict-free cols)
    const int tid = threadIdx.x;
    const int n0 = blockIdx.x * 64;
    const int b = blockIdx.y;
    const float4* src = (const float4*)(in + ((size_t)b * NBOX + n0) * NCLSIN);
    for (int t = tid; t < 64 * NCLSIN / 4; t += NTH) {   // 1456 float4
        float4 v = src[t];
        int e = t * 4;
#pragma unroll
        for (int q = 0; q < 4; ++q) {
            int ee = e + q;
            tile[(ee / NCLSIN) * 93 + (ee % NCLSIN)] = ((const float*)&v)[q];
        }
    }
    __syncthreads();
    const int wv = tid >> 6, ln = tid & 63;
    for (int c0 = wv; c0 < NCLS; c0 += 4) {
        float s = tile[ln * 93 + (c0 + 1)];
        bool hit = s > T0;
        unsigned long long mb = __ballot(hit);
        if (mb) {
            int nh = (int)__popcll(mb);
            int base = 0;
            if (ln == 0) base = atomicAdd(&cnt_g[b * NCLS + c0], nh);
            base = __shfl(base, 0, 64);
            if (hit) {
                int rank = (int)__popcll(mb & ((1ull << ln) - 1ull));
                int pos = base + rank;
                if (pos < CAP) {
                    unsigned i = (unsigned)(n0 + ln);
                    cand_g[(size_t)(b * NCLS + c0) * CAP + pos] =
                        ((unsigned long long)fmap(s) << 32) | (0xFFFFFFFFu - i);
                }
            }
        }
    }
}

// sort cand[0..M) desc (pad to pow2 with 0), gather boxes, serial greedy walk
// on wave 0 (selected boxes live in 2 register slots/lane). Broadcasts nsel.
__device__ __forceinline__ void sort_gather_walk(
    unsigned long long* cand, float4* candbox, int M,
    const float4* __restrict__ bbase, int tid,
    float4& sel0, float4& sel1, float& sa0, float& sa1,
    float& ss0, float& ss1, int& nsel, int* sh_nsel) {
    int P = 1;
    while (P < M) P <<= 1;
    for (int i = M + tid; i < P; i += NTH) cand[i] = 0ull;
    __syncthreads();
    for (int kk = 2; kk <= P; kk <<= 1) {
        for (int jj = kk >> 1; jj > 0; jj >>= 1) {
            for (int i = tid; i < P; i += NTH) {
                int ixj = i ^ jj;
                if (ixj > i) {
                    unsigned long long a = cand[i], c = cand[ixj];
                    bool sw = ((i & kk) == 0) ? (a < c) : (a > c);
                    if (sw) { cand[i] = c; cand[ixj] = a; }
                }
            }
            __syncthreads();
        }
    }
    const int PBX = M < CBCAP ? M : CBCAP;
    for (int i = tid; i < PBX; i += NTH)
        candbox[i] = bbase[(int)(0xFFFFFFFFu - (unsigned)cand[i])];
    __syncthreads();
    if (tid < 64) {
        for (int m = 0; m < M && nsel < MAXSEL; ++m) {
            unsigned long long key = cand[m];
            float4 bx = (m < CBCAP) ? candbox[m]
                                    : bbase[(int)(0xFFFFFFFFu - (unsigned)key)];
            float ca = __fmul_rn(__fsub_rn(bx.z, bx.x), __fsub_rn(bx.w, bx.y));
            bool sup = false;
            if (tid < nsel) sup = sup_test(sel0, sa0, bx, ca);
            if (tid + 64 < nsel) sup = sup || sup_test(sel1, sa1, bx, ca);
            if (!__any(sup)) {
                if (tid == nsel) { sel0 = bx; sa0 = ca; ss0 = funmap((unsigned)(key >> 32)); }
                if (tid == nsel - 64) { sel1 = bx; sa1 = ca; ss1 = funmap((unsigned)(key >> 32)); }
                nsel++;
            }
        }
        if (tid == 0) *sh_nsel = nsel;
    }
    __syncthreads();
    nsel = *sh_nsel;
    __syncthreads();
}

// ---------------------------------------------------------------------------
// Kernel 1: one block per (batch, class). Common case: sort+walk the band
// list only. Exact refill via adaptive radix-select over raw strided scores
// (probability ~0, preserves exactness).
// ---------------------------------------------------------------------------
__global__ __launch_bounds__(NTH) void nms_k(
    const unsigned long long* __restrict__ cand_g,
    const int* __restrict__ cnt_g,
    const float* __restrict__ scores_raw,
    const float4* __restrict__ boxes,
    float* __restrict__ ws_sc, float* __restrict__ ws_bx, int use_band) {
    __shared__ unsigned hist[BINS];
    __shared__ unsigned gbuf[NTH];
    __shared__ unsigned long long cand[CAP];
    __shared__ float4 candbox[CBCAP];
    __shared__ unsigned sh_kmax, sh_pb;
    __shared__ int sh_E, sh_g, sh_b, sh_cnt, sh_nsel;

    const int tid = threadIdx.x;
    const int c0 = blockIdx.x;
    const int b = blockIdx.y;
    const int bc = b * NCLS + c0;
    const float* sraw = scores_raw + (size_t)b * NBOX * NCLSIN + (c0 + 1);
    const float4* bbase = boxes + (size_t)b * NBOX;

    float4 sel0 = make_float4(0.f, 0.f, 0.f, 0.f);
    float4 sel1 = make_float4(0.f, 0.f, 0.f, 0.f);
    float sa0 = 0.f, sa1 = 0.f, ss0 = 0.f, ss1 = 0.f;
    int nsel = 0;
    unsigned long long lastk = ~0ull;

    if (use_band) {
        const int C = cnt_g[bc];
        if (C > 0 && C <= CAP) {
            for (int i = tid; i < C; i += NTH)
                cand[i] = cand_g[(size_t)bc * CAP + i];
            sort_gather_walk(cand, candbox, C, bbase, tid,
                             sel0, sel1, sa0, sa1, ss0, ss1, nsel, &sh_nsel);
            lastk = cand[C - 1];  // smallest band key (sorted, zeros after C)
        }
        // C==0 or C>CAP: lastk stays ~0 -> exact full fallback below
    }

    while (nsel < MAXSEL) {
        // ---- pass 1: eligible count + max key (keys strictly below lastk) ----
        unsigned km = 0, ce = 0;
        for (int i = tid; i < NBOX; i += NTH) {
            float s = sraw[(size_t)i * NCLSIN];
            unsigned k = (s > 0.3f) ? fmap(s) : 0u;
            if (k) {
                unsigned long long key =
                    ((unsigned long long)k << 32) | (0xFFFFFFFFu - (unsigned)i);
                if (key < lastk) { ce++; km = km > k ? km : k; }
            }
        }
#pragma unroll
        for (int off = 32; off > 0; off >>= 1) {
            unsigned o = (unsigned)__shfl_xor((int)km, off, 64);
            km = km > o ? km : o;
            ce += (unsigned)__shfl_xor((int)ce, off, 64);
        }
        if ((tid & 63) == 0) { gbuf[tid >> 6] = km; gbuf[8 + (tid >> 6)] = ce; }
        __syncthreads();
        if (tid == 0) {
            unsigned m2 = 0, c2 = 0;
            for (int w = 0; w < NTH / 64; ++w) {
                m2 = m2 > gbuf[w] ? m2 : gbuf[w];
                c2 += gbuf[8 + w];
            }
            sh_kmax = m2; sh_E = (int)c2;
        }
        __syncthreads();
        const int E = sh_E;
        const unsigned kmax = sh_kmax;
        if (E == 0) break;

        unsigned thr = 1u;
        if (E > TSEL) {
            for (int shift = 8;; shift += 4) {
                for (int i = tid; i < BINS; i += NTH) hist[i] = 0u;
                __syncthreads();
                for (int i = tid; i < NBOX; i += NTH) {
                    float s = sraw[(size_t)i * NCLSIN];
                    unsigned k = (s > 0.3f) ? fmap(s) : 0u;
                    if (k) {
                        unsigned long long key =
                            ((unsigned long long)k << 32) | (0xFFFFFFFFu - (unsigned)i);
                        if (key < lastk) {
                            unsigned bin = (kmax - k) >> shift;
                            if (bin < BINS - 1) atomicAdd(&hist[bin], 1u);
                        }
                    }
                }
                __syncthreads();
                bin_select(hist, gbuf, &sh_g, &sh_b, &sh_pb, tid, (unsigned)TSEL);
                if (sh_b < BINS - 1) {
                    long long t = (long long)kmax - ((long long)(sh_b + 1) << shift) + 1;
                    thr = (t < 1) ? 1u : (unsigned)t;
                    break;
                }
            }
        }

        if (tid == 0) sh_cnt = 0;
        __syncthreads();
        for (int i = tid; i < NBOX; i += NTH) {
            float s = sraw[(size_t)i * NCLSIN];
            unsigned k = (s > 0.3f) ? fmap(s) : 0u;
            if (k >= thr) {
                unsigned long long key =
                    ((unsigned long long)k << 32) | (0xFFFFFFFFu - (unsigned)i);
                if (key < lastk) {
                    int pos = atomicAdd(&sh_cnt, 1);
                    if (pos < CAP) cand[pos] = key;
                }
            }
        }
        __syncthreads();
        const int M = sh_cnt < CAP ? sh_cnt : CAP;

        sort_gather_walk(cand, candbox, M, bbase, tid,
                         sel0, sel1, sa0, sa1, ss0, ss1, nsel, &sh_nsel);
        if (nsel >= MAXSEL || E <= M) break;
        lastk = cand[M - 1];
        __syncthreads();
    }

    // ---- outputs: selections in greedy order, zero-padded ----
    if (tid < 64) {
        float* scp = ws_sc + (size_t)bc * MAXSEL;
        float4* bxp = (float4*)(ws_bx + (size_t)bc * MAXSEL * 4);
        {
            bool v = tid < nsel;
            scp[tid] = v ? ss0 : 0.f;
            bxp[tid] = v ? sel0 : make_float4(0.f, 0.f, 0.f, 0.f);
        }
        int j1 = tid + 64;
        if (j1 < MAXSEL) {
            bool v = j1 < nsel;
            scp[j1] = v ? ss1 : 0.f;
            bxp[j1] = v ? sel1 : make_float4(0.f, 0.f, 0.f, 0.f);
        }
    }
}

// ---------------------------------------------------------------------------
// Kernel 2: one block per batch: stable top-200 of 9000 via radix-select+sort.
// ---------------------------------------------------------------------------
__global__ __launch_bounds__(NTH) void topk_k(const float* __restrict__ ws_sc,
                                              const float* __restrict__ ws_bx,
                                              float* __restrict__ out_sc,
                                              float* __restrict__ out_bx) {
    __shared__ unsigned hist[BINS];
    __shared__ unsigned gbuf[NTH];
    __shared__ unsigned long long cand[CAP];
    __shared__ unsigned sh_kmax, sh_pb;
    __shared__ int sh_E, sh_g, sh_b, sh_cnt;

    const int tid = threadIdx.x;
    const int b = blockIdx.x;
    const int NF = NCLS * MAXSEL;  // 9000
    const float* sp = ws_sc + (size_t)b * NF;

    unsigned km = 0, ce = 0;
    for (int f = tid; f < NF; f += NTH) {
        unsigned k = __float_as_uint(sp[f]);
        if (k) { ce++; km = km > k ? km : k; }
    }
#pragma unroll
    for (int off = 32; off > 0; off >>= 1) {
        unsigned o = (unsigned)__shfl_xor((int)km, off, 64);
        km = km > o ? km : o;
        ce += (unsigned)__shfl_xor((int)ce, off, 64);
    }
    if ((tid & 63) == 0) { gbuf[tid >> 6] = km; gbuf[8 + (tid >> 6)] = ce; }
    __syncthreads();
    if (tid == 0) {
        unsigned m2 = 0, c2 = 0;
        for (int w = 0; w < NTH / 64; ++w) {
            m2 = m2 > gbuf[w] ? m2 : gbuf[w];
            c2 += gbuf[8 + w];
        }
        sh_kmax = m2; sh_E = (int)c2;
    }
    __syncthreads();
    const int E = sh_E;
    const unsigned kmax = sh_kmax;

    unsigned thr = 1u;
    if (E > TOPK) {
        for (int shift = 8;; shift += 4) {
            for (int i = tid; i < BINS; i += NTH) hist[i] = 0u;
            __syncthreads();
            for (int f = tid; f < NF; f += NTH) {
                unsigned k = __float_as_uint(sp[f]);
                if (k) {
                    unsigned bin = (kmax - k) >> shift;
                    if (bin < BINS - 1) atomicAdd(&hist[bin], 1u);
                }
            }
            __syncthreads();
            bin_select(hist, gbuf, &sh_g, &sh_b, &sh_pb, tid, (unsigned)TOPK);
            if (sh_b < BINS - 1) {
                long long t = (long long)kmax - ((long long)(sh_b + 1) << shift) + 1;
                thr = (t < 1) ? 1u : (unsigned)t;
                break;
            }
        }
    }

    if (tid == 0) sh_cnt = 0;
    __syncthreads();
    for (int f = tid; f < NF; f += NTH) {
        unsigned k = __float_as_uint(sp[f]);
        if (k >= thr) {
            int pos = atomicAdd(&sh_cnt, 1);
            if (pos < CAP)
                cand[pos] = ((unsigned long long)k << 32) | (0xFFFFFFFFu - (unsigned)f);
        }
    }
    __syncthreads();
    int M = sh_cnt < CAP ? sh_cnt : CAP;

    if (M < TOPK) {
        int lim = M + TOPK;
        if (lim > NF) lim = NF;
        for (int f = tid; f < lim; f += NTH) {
            unsigned k = __float_as_uint(sp[f]);
            if (k == 0) {
                int pos = atomicAdd(&sh_cnt, 1);
                if (pos < CAP)
                    cand[pos] = (unsigned long long)(0xFFFFFFFFu - (unsigned)f);
            }
        }
        __syncthreads();
        M = sh_cnt < CAP ? sh_cnt : CAP;
    }

    int P = 1;
    while (P < M) P <<= 1;
    for (int i = M + tid; i < P; i += NTH) cand[i] = 0ull;
    __syncthreads();
    for (int kk = 2; kk <= P; kk <<= 1) {
        for (int jj = kk >> 1; jj > 0; jj >>= 1) {
            for (int i = tid; i < P; i += NTH) {
                int ixj = i ^ jj;
                if (ixj > i) {
                    unsigned long long a = cand[i], c = cand[ixj];
                    bool sw = ((i & kk) == 0) ? (a < c) : (a > c);
                    if (sw) { cand[i] = c; cand[ixj] = a; }
                }
            }
            __syncthreads();
        }
    }

    for (int k = tid; k < TOPK; k += NTH) {
        float cls = 0.f, s = 0.f;
        float4 bx = make_float4(0.f, 0.f, 0.f, 0.f);
        if (k < M) {
            unsigned long long key = cand[k];
            unsigned f = 0xFFFFFFFFu - (unsigned)key;
            s = __uint_as_float((unsigned)(key >> 32));
            cls = (s > 0.f) ? (float)(f / MAXSEL + 1) : 0.f;
            bx = *(const float4*)(ws_bx + ((size_t)b * NF + f) * 4);
        }
        out_sc[((size_t)b * TOPK + k) * 2 + 0] = cls;
        out_sc[((size_t)b * TOPK + k) * 2 + 1] = s;
        ((float4*)out_bx)[(size_t)b * TOPK + k] = bx;
    }
}

// ---------------------------------------------------------------------------
extern "C" void kernel_launch(void* const* d_in, const int* in_sizes, int n_in,
                              void* d_out, int out_size, void* d_ws, size_t ws_size,
                              hipStream_t stream) {
    const float* scores = (const float*)d_in[0];
    const float4* boxes = (const float4*)d_in[1];
    float* out = (float*)d_out;

    const int B = in_sizes[1] / (NBOX * 4);
    const int NBC = B * NCLS;

    // ws layout: cnt [NBC int] | cand [NBC*CAP u64] | ws_sc | ws_bx
    size_t off_cand = (((size_t)NBC * 4) + 15) & ~(size_t)15;
    size_t off_sc = off_cand + (size_t)NBC * CAP * 8;
    size_t off_bx = off_sc + (size_t)NBC * MAXSEL * 4;
    size_t need = off_bx + (size_t)NBC * MAXSEL * 16;

    char* ws = (char*)d_ws;
    bool use_band = ws_size >= need;

    int* cnt_g;
    unsigned long long* cand_g;
    float *ws_sc, *ws_bx;
    if (use_band) {
        cnt_g = (int*)ws;
        cand_g = (unsigned long long*)(ws + off_cand);
        ws_sc = (float*)(ws + off_sc);
        ws_bx = (float*)(ws + off_bx);
    } else {
        cnt_g = (int*)ws;           // unused
        cand_g = (unsigned long long*)ws;  // unused
        ws_sc = (float*)ws;
        ws_bx = ws_sc + (size_t)NBC * MAXSEL;
    }

    if (use_band) {
        hipMemsetAsync(cnt_g, 0, (size_t)NBC * 4, stream);
        filter_k<<<dim3(NBOX / 64, B), NTH, 0, stream>>>(scores, cand_g, cnt_g);
    }
    nms_k<<<dim3(NCLS, B), NTH, 0, stream>>>(cand_g, cnt_g, scores, boxes,
                                             ws_sc, ws_bx, use_band ? 1 : 0);
    topk_k<<<B, NTH, 0, stream>>>(ws_sc, ws_bx, out, out + (size_t)B * TOPK * 2);
}

// Round 4
// 126.889 us; speedup vs baseline: 2.2927x; 2.2927x over previous
//
#include <hip/hip_runtime.h>

#define NTH 256
#define NBOX 16384
#define NCLSIN 91
#define NCLS 90
#define MAXSEL 100
#define TOPK 200
#define TSEL 256      // fallback radix-select size
#define CAP 1024      // candidate list capacity per (b,c)
#define CBCAP 512     // prefetched candidate boxes
#define BINS 2048
#define GRP 8         // BINS / NTH
#define T0 0.985f     // band threshold: E[hits/class]=246; exact refill guards
#define BOXPB 256     // boxes per filter block
#define KSL 16        // per-class LDS slots per filter block (mean 3.84 hits)
#define OVFC 64       // LDS overflow list capacity
#define CNTSTR 16     // cnt_g stride in ints (64B: one cacheline per counter)

// order-preserving fp32 <-> u32 (strictly monotone for all non-NaN)
__device__ __forceinline__ unsigned fmap(float f) {
    unsigned u = __float_as_uint(f);
    return (u & 0x80000000u) ? ~u : (u | 0x80000000u);
}
__device__ __forceinline__ float funmap(unsigned u) {
    unsigned b = (u & 0x80000000u) ? (u ^ 0x80000000u) : ~u;
    return __uint_as_float(b);
}

// exact reference IoU>0.5 test (same op order, real IEEE div, no FMA)
__device__ __forceinline__ bool sup_test(float4 s, float sa, float4 c, float ca) {
    float y1 = fmaxf(s.x, c.x);
    float x1 = fmaxf(s.y, c.y);
    float y2 = fminf(s.z, c.z);
    float x2 = fminf(s.w, c.w);
    float dy = fmaxf(__fsub_rn(y2, y1), 0.f);
    float dx = fmaxf(__fsub_rn(x2, x1), 0.f);
    float inter = __fmul_rn(dy, dx);
    float uni = __fsub_rn(__fadd_rn(sa, ca), inter);
    return (uni > 0.f) && (__fdiv_rn(inter, uni) > 0.5f);
}

__device__ __forceinline__ void bin_select(unsigned* hist, unsigned* gbuf,
                                           int* sh_g, int* sh_b, unsigned* sh_pb,
                                           int tid, unsigned need) {
    unsigned gs = 0;
#pragma unroll
    for (int q = 0; q < GRP; ++q) gs += hist[tid * GRP + q];
    gbuf[tid] = gs;
    __syncthreads();
    for (int off = 1; off < NTH; off <<= 1) {
        unsigned add = (tid >= off) ? gbuf[tid - off] : 0u;
        __syncthreads();
        gbuf[tid] += add;
        __syncthreads();
    }
    if (tid == 0) *sh_g = NTH - 1;
    __syncthreads();
    if (gbuf[tid] >= need && (tid == 0 || gbuf[tid - 1] < need)) *sh_g = tid;
    __syncthreads();
    if (tid == 0) {
        int g = *sh_g;
        unsigned acc = (g > 0) ? gbuf[g - 1] : 0u;
        int bs = g * GRP + (GRP - 1);
        unsigned pb = acc;
#pragma unroll
        for (int q = 0; q < GRP; ++q) {
            acc += hist[g * GRP + q];
            if (acc >= need) { bs = g * GRP + q; pb = acc; break; }
            pb = acc;
        }
        *sh_b = bs; *sh_pb = pb;
    }
    __syncthreads();
}

// ---------------------------------------------------------------------------
// Kernel 0: stream scores once (coalesced float4). Hits (s > T0) stage into
// per-class LDS slots (LDS-atomic rank); one parallel global atomicAdd per
// class per block reserves space; scatter writes. No transpose, no ballots.
// ---------------------------------------------------------------------------
__global__ __launch_bounds__(NTH) void filter_k(const float* __restrict__ in,
                                                unsigned long long* __restrict__ cand_g,
                                                int* __restrict__ cnt_g) {
    __shared__ int cnt_s[NCLSIN];                      // per-class hit count (class 0 unused)
    __shared__ int base_s[NCLSIN];
    __shared__ unsigned long long ent[NCLSIN * KSL];   // 11.6 KB
    __shared__ unsigned ovf_meta[OVFC];                // (c<<16)|rank
    __shared__ unsigned long long ovf_key[OVFC];
    __shared__ int sh_ovf;

    const int tid = threadIdx.x;
    const int n0 = blockIdx.x * BOXPB;
    const int b = blockIdx.y;
    const int NF4 = BOXPB * NCLSIN / 4;  // 5824 float4 per block

    for (int i = tid; i < NCLSIN; i += NTH) cnt_s[i] = 0;
    if (tid == 0) sh_ovf = 0;
    __syncthreads();

    const float4* src = (const float4*)(in + ((size_t)b * NBOX + n0) * NCLSIN);
    for (int t = tid; t < NF4; t += NTH) {
        float4 v = src[t];
        float mx = fmaxf(fmaxf(v.x, v.y), fmaxf(v.z, v.w));
        if (mx > T0) {
            const float sv[4] = {v.x, v.y, v.z, v.w};
            int e = t * 4;
#pragma unroll
            for (int q = 0; q < 4; ++q) {
                float s = sv[q];
                if (s > T0) {
                    int ee = e + q;
                    int row = ee / NCLSIN;        // magic-mul
                    int c = ee - row * NCLSIN;    // class id (0 = background)
                    if (c) {
                        int r = atomicAdd(&cnt_s[c], 1);
                        unsigned i = (unsigned)(n0 + row);
                        unsigned long long key =
                            ((unsigned long long)fmap(s) << 32) | (0xFFFFFFFFu - i);
                        if (r < KSL) {
                            ent[c * KSL + r] = key;
                        } else {
                            int o = atomicAdd(&sh_ovf, 1);
                            if (o < OVFC) {
                                ovf_meta[o] = ((unsigned)c << 16) | (unsigned)r;
                                ovf_key[o] = key;
                            } else {
                                // astronomically rare: force exact full fallback
                                atomicAdd(&cnt_g[(b * NCLS + c - 1) * CNTSTR], CAP + 1);
                            }
                        }
                    }
                }
            }
        }
    }
    __syncthreads();

    // Phase B: one atomic per non-empty class, all issued in parallel
    if (tid >= 1 && tid < NCLSIN) {
        int c = tid;
        int n = cnt_s[c];
        int base = 0;
        if (n > 0) {
            int bc = b * NCLS + c - 1;
            base = atomicAdd(&cnt_g[bc * CNTSTR], n);
            int lim = n < KSL ? n : KSL;
            for (int j = 0; j < lim; ++j) {
                int pos = base + j;
                if (pos < CAP) cand_g[(size_t)bc * CAP + pos] = ent[c * KSL + j];
            }
        }
        base_s[c] = base;
    }
    __syncthreads();

    int no = sh_ovf < OVFC ? sh_ovf : OVFC;
    for (int o = tid; o < no; o += NTH) {
        unsigned m = ovf_meta[o];
        int c = (int)(m >> 16);
        int r = (int)(m & 0xFFFFu);
        int bc = b * NCLS + c - 1;
        int pos = base_s[c] + r;
        if (pos < CAP) cand_g[(size_t)bc * CAP + pos] = ovf_key[o];
    }
}

// sort cand[0..M) desc (pad to pow2 with 0), gather boxes, serial greedy walk
// on wave 0 (selected boxes live in 2 register slots/lane). Broadcasts nsel.
__device__ __forceinline__ void sort_gather_walk(
    unsigned long long* cand, float4* candbox, int M,
    const float4* __restrict__ bbase, int tid,
    float4& sel0, float4& sel1, float& sa0, float& sa1,
    float& ss0, float& ss1, int& nsel, int* sh_nsel) {
    int P = 1;
    while (P < M) P <<= 1;
    for (int i = M + tid; i < P; i += NTH) cand[i] = 0ull;
    __syncthreads();
    for (int kk = 2; kk <= P; kk <<= 1) {
        for (int jj = kk >> 1; jj > 0; jj >>= 1) {
            for (int i = tid; i < P; i += NTH) {
                int ixj = i ^ jj;
                if (ixj > i) {
                    unsigned long long a = cand[i], c = cand[ixj];
                    bool sw = ((i & kk) == 0) ? (a < c) : (a > c);
                    if (sw) { cand[i] = c; cand[ixj] = a; }
                }
            }
            __syncthreads();
        }
    }
    const int PBX = M < CBCAP ? M : CBCAP;
    for (int i = tid; i < PBX; i += NTH)
        candbox[i] = bbase[(int)(0xFFFFFFFFu - (unsigned)cand[i])];
    __syncthreads();
    if (tid < 64) {
        for (int m = 0; m < M && nsel < MAXSEL; ++m) {
            unsigned long long key = cand[m];
            float4 bx = (m < CBCAP) ? candbox[m]
                                    : bbase[(int)(0xFFFFFFFFu - (unsigned)key)];
            float ca = __fmul_rn(__fsub_rn(bx.z, bx.x), __fsub_rn(bx.w, bx.y));
            bool sup = false;
            if (tid < nsel) sup = sup_test(sel0, sa0, bx, ca);
            if (tid + 64 < nsel) sup = sup || sup_test(sel1, sa1, bx, ca);
            if (!__any(sup)) {
                if (tid == nsel) { sel0 = bx; sa0 = ca; ss0 = funmap((unsigned)(key >> 32)); }
                if (tid == nsel - 64) { sel1 = bx; sa1 = ca; ss1 = funmap((unsigned)(key >> 32)); }
                nsel++;
            }
        }
        if (tid == 0) *sh_nsel = nsel;
    }
    __syncthreads();
    nsel = *sh_nsel;
    __syncthreads();
}

// ---------------------------------------------------------------------------
// Kernel 1: one block per (batch, class). Common case: sort+walk the band
// list only. Exact refill via adaptive radix-select over raw strided scores.
// ---------------------------------------------------------------------------
__global__ __launch_bounds__(NTH) void nms_k(
    const unsigned long long* __restrict__ cand_g,
    const int* __restrict__ cnt_g,
    const float* __restrict__ scores_raw,
    const float4* __restrict__ boxes,
    float* __restrict__ ws_sc, float* __restrict__ ws_bx, int use_band) {
    __shared__ unsigned hist[BINS];
    __shared__ unsigned gbuf[NTH];
    __shared__ unsigned long long cand[CAP];
    __shared__ float4 candbox[CBCAP];
    __shared__ unsigned sh_kmax, sh_pb;
    __shared__ int sh_E, sh_g, sh_b, sh_cnt, sh_nsel;

    const int tid = threadIdx.x;
    const int c0 = blockIdx.x;
    const int b = blockIdx.y;
    const int bc = b * NCLS + c0;
    const float* sraw = scores_raw + (size_t)b * NBOX * NCLSIN + (c0 + 1);
    const float4* bbase = boxes + (size_t)b * NBOX;

    float4 sel0 = make_float4(0.f, 0.f, 0.f, 0.f);
    float4 sel1 = make_float4(0.f, 0.f, 0.f, 0.f);
    float sa0 = 0.f, sa1 = 0.f, ss0 = 0.f, ss1 = 0.f;
    int nsel = 0;
    unsigned long long lastk = ~0ull;

    if (use_band) {
        const int C = cnt_g[bc * CNTSTR];
        if (C > 0 && C <= CAP) {
            for (int i = tid; i < C; i += NTH)
                cand[i] = cand_g[(size_t)bc * CAP + i];
            sort_gather_walk(cand, candbox, C, bbase, tid,
                             sel0, sel1, sa0, sa1, ss0, ss1, nsel, &sh_nsel);
            lastk = cand[C - 1];  // smallest band key; all non-band keys are below
        }
        // C==0 or C>CAP: lastk stays ~0 -> exact full fallback below
    }

    while (nsel < MAXSEL) {
        // ---- pass 1: eligible count + max key (keys strictly below lastk) ----
        unsigned km = 0, ce = 0;
        for (int i = tid; i < NBOX; i += NTH) {
            float s = sraw[(size_t)i * NCLSIN];
            unsigned k = (s > 0.3f) ? fmap(s) : 0u;
            if (k) {
                unsigned long long key =
                    ((unsigned long long)k << 32) | (0xFFFFFFFFu - (unsigned)i);
                if (key < lastk) { ce++; km = km > k ? km : k; }
            }
        }
#pragma unroll
        for (int off = 32; off > 0; off >>= 1) {
            unsigned o = (unsigned)__shfl_xor((int)km, off, 64);
            km = km > o ? km : o;
            ce += (unsigned)__shfl_xor((int)ce, off, 64);
        }
        if ((tid & 63) == 0) { gbuf[tid >> 6] = km; gbuf[8 + (tid >> 6)] = ce; }
        __syncthreads();
        if (tid == 0) {
            unsigned m2 = 0, c2 = 0;
            for (int w = 0; w < NTH / 64; ++w) {
                m2 = m2 > gbuf[w] ? m2 : gbuf[w];
                c2 += gbuf[8 + w];
            }
            sh_kmax = m2; sh_E = (int)c2;
        }
        __syncthreads();
        const int E = sh_E;
        const unsigned kmax = sh_kmax;
        if (E == 0) break;

        unsigned thr = 1u;
        if (E > TSEL) {
            for (int shift = 8;; shift += 4) {
                for (int i = tid; i < BINS; i += NTH) hist[i] = 0u;
                __syncthreads();
                for (int i = tid; i < NBOX; i += NTH) {
                    float s = sraw[(size_t)i * NCLSIN];
                    unsigned k = (s > 0.3f) ? fmap(s) : 0u;
                    if (k) {
                        unsigned long long key =
                            ((unsigned long long)k << 32) | (0xFFFFFFFFu - (unsigned)i);
                        if (key < lastk) {
                            unsigned bin = (kmax - k) >> shift;
                            if (bin < BINS - 1) atomicAdd(&hist[bin], 1u);
                        }
                    }
                }
                __syncthreads();
                bin_select(hist, gbuf, &sh_g, &sh_b, &sh_pb, tid, (unsigned)TSEL);
                if (sh_b < BINS - 1) {
                    long long t = (long long)kmax - ((long long)(sh_b + 1) << shift) + 1;
                    thr = (t < 1) ? 1u : (unsigned)t;
                    break;
                }
            }
        }

        if (tid == 0) sh_cnt = 0;
        __syncthreads();
        for (int i = tid; i < NBOX; i += NTH) {
            float s = sraw[(size_t)i * NCLSIN];
            unsigned k = (s > 0.3f) ? fmap(s) : 0u;
            if (k >= thr) {
                unsigned long long key =
                    ((unsigned long long)k << 32) | (0xFFFFFFFFu - (unsigned)i);
                if (key < lastk) {
                    int pos = atomicAdd(&sh_cnt, 1);
                    if (pos < CAP) cand[pos] = key;
                }
            }
        }
        __syncthreads();
        const int M = sh_cnt < CAP ? sh_cnt : CAP;

        sort_gather_walk(cand, candbox, M, bbase, tid,
                         sel0, sel1, sa0, sa1, ss0, ss1, nsel, &sh_nsel);
        if (nsel >= MAXSEL || E <= M) break;
        lastk = cand[M - 1];
        __syncthreads();
    }

    // ---- outputs: selections in greedy order, zero-padded ----
    if (tid < 64) {
        float* scp = ws_sc + (size_t)bc * MAXSEL;
        float4* bxp = (float4*)(ws_bx + (size_t)bc * MAXSEL * 4);
        {
            bool v = tid < nsel;
            scp[tid] = v ? ss0 : 0.f;
            bxp[tid] = v ? sel0 : make_float4(0.f, 0.f, 0.f, 0.f);
        }
        int j1 = tid + 64;
        if (j1 < MAXSEL) {
            bool v = j1 < nsel;
            scp[j1] = v ? ss1 : 0.f;
            bxp[j1] = v ? sel1 : make_float4(0.f, 0.f, 0.f, 0.f);
        }
    }
}

// ---------------------------------------------------------------------------
// Kernel 2: one block per batch: stable top-200 of 9000 via radix-select+sort.
// ---------------------------------------------------------------------------
__global__ __launch_bounds__(NTH) void topk_k(const float* __restrict__ ws_sc,
                                              const float* __restrict__ ws_bx,
                                              float* __restrict__ out_sc,
                                              float* __restrict__ out_bx) {
    __shared__ unsigned hist[BINS];
    __shared__ unsigned gbuf[NTH];
    __shared__ unsigned long long cand[CAP];
    __shared__ unsigned sh_kmax, sh_pb;
    __shared__ int sh_E, sh_g, sh_b, sh_cnt;

    const int tid = threadIdx.x;
    const int b = blockIdx.x;
    const int NF = NCLS * MAXSEL;  // 9000
    const float* sp = ws_sc + (size_t)b * NF;

    unsigned km = 0, ce = 0;
    for (int f = tid; f < NF; f += NTH) {
        unsigned k = __float_as_uint(sp[f]);
        if (k) { ce++; km = km > k ? km : k; }
    }
#pragma unroll
    for (int off = 32; off > 0; off >>= 1) {
        unsigned o = (unsigned)__shfl_xor((int)km, off, 64);
        km = km > o ? km : o;
        ce += (unsigned)__shfl_xor((int)ce, off, 64);
    }
    if ((tid & 63) == 0) { gbuf[tid >> 6] = km; gbuf[8 + (tid >> 6)] = ce; }
    __syncthreads();
    if (tid == 0) {
        unsigned m2 = 0, c2 = 0;
        for (int w = 0; w < NTH / 64; ++w) {
            m2 = m2 > gbuf[w] ? m2 : gbuf[w];
            c2 += gbuf[8 + w];
        }
        sh_kmax = m2; sh_E = (int)c2;
    }
    __syncthreads();
    const int E = sh_E;
    const unsigned kmax = sh_kmax;

    unsigned thr = 1u;
    if (E > TOPK) {
        for (int shift = 8;; shift += 4) {
            for (int i = tid; i < BINS; i += NTH) hist[i] = 0u;
            __syncthreads();
            for (int f = tid; f < NF; f += NTH) {
                unsigned k = __float_as_uint(sp[f]);
                if (k) {
                    unsigned bin = (kmax - k) >> shift;
                    if (bin < BINS - 1) atomicAdd(&hist[bin], 1u);
                }
            }
            __syncthreads();
            bin_select(hist, gbuf, &sh_g, &sh_b, &sh_pb, tid, (unsigned)TOPK);
            if (sh_b < BINS - 1) {
                long long t = (long long)kmax - ((long long)(sh_b + 1) << shift) + 1;
                thr = (t < 1) ? 1u : (unsigned)t;
                break;
            }
        }
    }

    if (tid == 0) sh_cnt = 0;
    __syncthreads();
    for (int f = tid; f < NF; f += NTH) {
        unsigned k = __float_as_uint(sp[f]);
        if (k >= thr) {
            int pos = atomicAdd(&sh_cnt, 1);
            if (pos < CAP)
                cand[pos] = ((unsigned long long)k << 32) | (0xFFFFFFFFu - (unsigned)f);
        }
    }
    __syncthreads();
    int M = sh_cnt < CAP ? sh_cnt : CAP;

    if (M < TOPK) {
        int lim = M + TOPK;
        if (lim > NF) lim = NF;
        for (int f = tid; f < lim; f += NTH) {
            unsigned k = __float_as_uint(sp[f]);
            if (k == 0) {
                int pos = atomicAdd(&sh_cnt, 1);
                if (pos < CAP)
                    cand[pos] = (unsigned long long)(0xFFFFFFFFu - (unsigned)f);
            }
        }
        __syncthreads();
        M = sh_cnt < CAP ? sh_cnt : CAP;
    }

    int P = 1;
    while (P < M) P <<= 1;
    for (int i = M + tid; i < P; i += NTH) cand[i] = 0ull;
    __syncthreads();
    for (int kk = 2; kk <= P; kk <<= 1) {
        for (int jj = kk >> 1; jj > 0; jj >>= 1) {
            for (int i = tid; i < P; i += NTH) {
                int ixj = i ^ jj;
                if (ixj > i) {
                    unsigned long long a = cand[i], c = cand[ixj];
                    bool sw = ((i & kk) == 0) ? (a < c) : (a > c);
                    if (sw) { cand[i] = c; cand[ixj] = a; }
                }
            }
            __syncthreads();
        }
    }

    for (int k = tid; k < TOPK; k += NTH) {
        float cls = 0.f, s = 0.f;
        float4 bx = make_float4(0.f, 0.f, 0.f, 0.f);
        if (k < M) {
            unsigned long long key = cand[k];
            unsigned f = 0xFFFFFFFFu - (unsigned)key;
            s = __uint_as_float((unsigned)(key >> 32));
            cls = (s > 0.f) ? (float)(f / MAXSEL + 1) : 0.f;
            bx = *(const float4*)(ws_bx + ((size_t)b * NF + f) * 4);
        }
        out_sc[((size_t)b * TOPK + k) * 2 + 0] = cls;
        out_sc[((size_t)b * TOPK + k) * 2 + 1] = s;
        ((float4*)out_bx)[(size_t)b * TOPK + k] = bx;
    }
}

// ---------------------------------------------------------------------------
extern "C" void kernel_launch(void* const* d_in, const int* in_sizes, int n_in,
                              void* d_out, int out_size, void* d_ws, size_t ws_size,
                              hipStream_t stream) {
    const float* scores = (const float*)d_in[0];
    const float4* boxes = (const float4*)d_in[1];
    float* out = (float*)d_out;

    const int B = in_sizes[1] / (NBOX * 4);
    const int NBC = B * NCLS;

    // ws layout: cnt [NBC * CNTSTR ints, 64B-padded] | cand [NBC*CAP u64] | sc | bx
    size_t off_cand = ((size_t)NBC * CNTSTR * 4 + 15) & ~(size_t)15;
    size_t off_sc = off_cand + (size_t)NBC * CAP * 8;
    size_t off_bx = off_sc + (size_t)NBC * MAXSEL * 4;
    size_t need = off_bx + (size_t)NBC * MAXSEL * 16;

    char* ws = (char*)d_ws;
    bool use_band = ws_size >= need;

    int* cnt_g;
    unsigned long long* cand_g;
    float *ws_sc, *ws_bx;
    if (use_band) {
        cnt_g = (int*)ws;
        cand_g = (unsigned long long*)(ws + off_cand);
        ws_sc = (float*)(ws + off_sc);
        ws_bx = (float*)(ws + off_bx);
    } else {
        cnt_g = (int*)ws;                  // unused
        cand_g = (unsigned long long*)ws;  // unused
        ws_sc = (float*)ws;
        ws_bx = ws_sc + (size_t)NBC * MAXSEL;
    }

    if (use_band) {
        hipMemsetAsync(cnt_g, 0, (size_t)NBC * CNTSTR * 4, stream);
        filter_k<<<dim3(NBOX / BOXPB, B), NTH, 0, stream>>>(scores, cand_g, cnt_g);
    }
    nms_k<<<dim3(NCLS, B), NTH, 0, stream>>>(cand_g, cnt_g, scores, boxes,
                                             ws_sc, ws_bx, use_band ? 1 : 0);
    topk_k<<<B, NTH, 0, stream>>>(ws_sc, ws_bx, out, out + (size_t)B * TOPK * 2);
}